// Round 1
// baseline (757.740 us; speedup 1.0000x reference)
//
#include <hip/hip_runtime.h>
#include <cstdint>

#define DEV __device__ __forceinline__

typedef __bf16 bf16x8 __attribute__((ext_vector_type(8)));
typedef float f32x4 __attribute__((ext_vector_type(4)));

DEV uint16_t f2bf(float f) {
  uint32_t u = __float_as_uint(f);
  u += 0x7FFFu + ((u >> 16) & 1u);
  return (uint16_t)(u >> 16);
}
DEV float bf2f(uint16_t h) { return __uint_as_float(((uint32_t)h) << 16); }

DEV void gload16(const void* g, void* l) {
  __builtin_amdgcn_global_load_lds((const __attribute__((address_space(1))) void*)g,
                                   (__attribute__((address_space(3))) void*)l, 16, 0, 0);
}

// ---------------- LayerNorm over C=768, fp32 in -> bf16 out ----------------
__global__ __launch_bounds__(256) void ln768(const float* __restrict__ x,
                                             const float* __restrict__ w,
                                             const float* __restrict__ b,
                                             uint16_t* __restrict__ out) {
  const size_t row = blockIdx.x;
  const float* xr = x + row * 768;
  const int t = threadIdx.x;
  float v0 = xr[t], v1 = xr[t + 256], v2 = xr[t + 512];
  float s = v0 + v1 + v2;
  float s2 = v0 * v0 + v1 * v1 + v2 * v2;
#pragma unroll
  for (int o = 32; o; o >>= 1) {
    s += __shfl_down(s, o);
    s2 += __shfl_down(s2, o);
  }
  __shared__ float sh[8];
  if ((t & 63) == 0) { sh[t >> 6] = s; sh[4 + (t >> 6)] = s2; }
  __syncthreads();
  s = sh[0] + sh[1] + sh[2] + sh[3];
  s2 = sh[4] + sh[5] + sh[6] + sh[7];
  const float mu = s * (1.f / 768.f);
  const float var = s2 * (1.f / 768.f) - mu * mu;
  const float rstd = rsqrtf(var + 1e-6f);
  uint16_t* orow = out + row * 768;
  orow[t]       = f2bf((v0 - mu) * rstd * w[t] + b[t]);
  orow[t + 256] = f2bf((v1 - mu) * rstd * w[t + 256] + b[t + 256]);
  orow[t + 512] = f2bf((v2 - mu) * rstd * w[t + 512] + b[t + 512]);
}

// ---------------- transpose fp32 [R,Cc] -> bf16 [Cc,R] ----------------
// grid = (Cc/32, R/32), block = (32,8)
__global__ __launch_bounds__(256) void transpose_f2b(const float* __restrict__ in,
                                                     uint16_t* __restrict__ outp,
                                                     int ldin, int ldout) {
  __shared__ float tile[32][33];
  const int tx = threadIdx.x, ty = threadIdx.y;
  const size_t x = (size_t)blockIdx.x * 32 + tx;
  const size_t y = (size_t)blockIdx.y * 32 + ty;
#pragma unroll
  for (int j = 0; j < 4; ++j) tile[ty + j * 8][tx] = in[(y + j * 8) * ldin + x];
  __syncthreads();
  const size_t x2 = (size_t)blockIdx.y * 32 + tx;
  const size_t y2 = (size_t)blockIdx.x * 32 + ty;
#pragma unroll
  for (int j = 0; j < 4; ++j) outp[(y2 + j * 8) * ldout + x2] = f2bf(tile[tx][ty + j * 8]);
}

// ---------------- transpose bf16 [R,Cc] -> bf16 [Cc,R] ----------------
__global__ __launch_bounds__(256) void transpose_b2b(const uint16_t* __restrict__ in,
                                                     uint16_t* __restrict__ outp,
                                                     int ldin, int ldout) {
  __shared__ uint16_t tile[32][33];
  const int tx = threadIdx.x, ty = threadIdx.y;
  const size_t x = (size_t)blockIdx.x * 32 + tx;
  const size_t y = (size_t)blockIdx.y * 32 + ty;
#pragma unroll
  for (int j = 0; j < 4; ++j) tile[ty + j * 8][tx] = in[(y + j * 8) * ldin + x];
  __syncthreads();
  const size_t x2 = (size_t)blockIdx.y * 32 + tx;
  const size_t y2 = (size_t)blockIdx.x * 32 + ty;
#pragma unroll
  for (int j = 0; j < 4; ++j) outp[(y2 + j * 8) * ldout + x2] = tile[tx][ty + j * 8];
}

// ---------------- row softmax over 256 cols (bf16 in-place), scale+clip ----------------
__global__ __launch_bounds__(256) void softmax256(uint16_t* __restrict__ p) {
  const int wave = threadIdx.x >> 6, lane = threadIdx.x & 63;
  const size_t row = (size_t)blockIdx.x * 4 + wave;
  uint16_t* pr = p + row * 256 + lane * 4;
  ushort4 u = *(const ushort4*)pr;
  float f0 = bf2f(u.x) * 0.125f, f1 = bf2f(u.y) * 0.125f;
  float f2 = bf2f(u.z) * 0.125f, f3 = bf2f(u.w) * 0.125f;
  f0 = fminf(fmaxf(f0, -50.f), 50.f);
  f1 = fminf(fmaxf(f1, -50.f), 50.f);
  f2 = fminf(fmaxf(f2, -50.f), 50.f);
  f3 = fminf(fmaxf(f3, -50.f), 50.f);
  float m = fmaxf(fmaxf(f0, f1), fmaxf(f2, f3));
#pragma unroll
  for (int o = 32; o; o >>= 1) m = fmaxf(m, __shfl_xor(m, o));
  float e0 = __expf(f0 - m), e1 = __expf(f1 - m), e2 = __expf(f2 - m), e3 = __expf(f3 - m);
  float s = e0 + e1 + e2 + e3;
#pragma unroll
  for (int o = 32; o; o >>= 1) s += __shfl_xor(s, o);
  const float inv = 1.f / s;
  ushort4 o4;
  o4.x = f2bf(e0 * inv); o4.y = f2bf(e1 * inv);
  o4.z = f2bf(e2 * inv); o4.w = f2bf(e3 * inv);
  *(ushort4*)pr = o4;
}

// ---------------- NT GEMM: C[M,N] = A[M,Kd] @ B[N,Kd]^T  (bf16 in, fp32 acc) ---------
// 2x2 waves, 16x16x32 MFMA, BK=32, global_load_lds staging. Optional z-batching:
// zhi = z/zdiv, zlo = z%zdiv; base += zhi*sXhi + zlo*sXlo (element strides).
template <int BM, int BN, bool OUTBF, bool HASBIAS, bool DOGELU, bool HASRES>
__global__ __launch_bounds__(256) void gemm_nt(
    const uint16_t* __restrict__ Abase, const uint16_t* __restrict__ Bbase,
    void* __restrict__ Cbase, const float* __restrict__ bias,
    const float* __restrict__ resbase, int Kd, int lda, int ldb, int ldc,
    int zdiv, size_t sAhi, size_t sAlo, size_t sBhi, size_t sBlo,
    size_t sChi, size_t sClo) {
  const int z = blockIdx.z;
  const int zhi = z / zdiv, zlo = z - zhi * zdiv;
  const uint16_t* A = Abase + zhi * sAhi + zlo * sAlo;
  const uint16_t* B = Bbase + zhi * sBhi + zlo * sBlo;
  const size_t coff = zhi * sChi + zlo * sClo;

  constexpr int WTM = BM / 2, WTN = BN / 2;
  constexpr int FM = WTM / 16, FN = WTN / 16;
  const int tid = threadIdx.x;
  const int wave = tid >> 6, lane = tid & 63;
  const int wm = wave >> 1, wn = wave & 1;
  const int l16 = lane & 15, lhi = lane >> 4;

  __shared__ __align__(16) uint16_t sA[BM * 32];
  __shared__ __align__(16) uint16_t sB[BN * 32];

  f32x4 acc[FM][FN];
#pragma unroll
  for (int m = 0; m < FM; ++m)
#pragma unroll
    for (int n = 0; n < FN; ++n) acc[m][n] = f32x4{0.f, 0.f, 0.f, 0.f};

  const int row0 = blockIdx.x * BM;
  const int col0 = blockIdx.y * BN;
  const int rr = tid >> 2, cq = tid & 3;

  for (int k0 = 0; k0 < Kd; k0 += 32) {
    __syncthreads();
#pragma unroll
    for (int is = 0; is < BM / 64; ++is) {
      const uint16_t* g = A + (size_t)(row0 + is * 64 + rr) * lda + k0 + cq * 8;
      gload16(g, &sA[is * 2048 + tid * 8]);
    }
#pragma unroll
    for (int is = 0; is < BN / 64; ++is) {
      const uint16_t* g = B + (size_t)(col0 + is * 64 + rr) * ldb + k0 + cq * 8;
      gload16(g, &sB[is * 2048 + tid * 8]);
    }
    __syncthreads();

    bf16x8 af[FM], bq[FN];
#pragma unroll
    for (int m = 0; m < FM; ++m)
      af[m] = *(const bf16x8*)(&sA[(wm * WTM + m * 16 + l16) * 32 + lhi * 8]);
#pragma unroll
    for (int n = 0; n < FN; ++n)
      bq[n] = *(const bf16x8*)(&sB[(wn * WTN + n * 16 + l16) * 32 + lhi * 8]);
#pragma unroll
    for (int m = 0; m < FM; ++m)
#pragma unroll
      for (int n = 0; n < FN; ++n)
        acc[m][n] = __builtin_amdgcn_mfma_f32_16x16x32_bf16(af[m], bq[n], acc[m][n], 0, 0, 0);
  }

  float* Cf = (float*)Cbase;
  uint16_t* Cb = (uint16_t*)Cbase;
#pragma unroll
  for (int m = 0; m < FM; ++m) {
#pragma unroll
    for (int n = 0; n < FN; ++n) {
      const int col = col0 + wn * WTN + n * 16 + l16;
      float bv = 0.f;
      if (HASBIAS) bv = bias[col];
#pragma unroll
      for (int r = 0; r < 4; ++r) {
        const int row = row0 + wm * WTM + m * 16 + lhi * 4 + r;
        float v = acc[m][n][r];
        if (HASBIAS) v += bv;
        if (DOGELU) v = 0.5f * v * (1.f + erff(v * 0.70710678118654752f));
        const size_t cidx = coff + (size_t)row * ldc + col;
        if (HASRES) v += resbase[cidx];
        if (OUTBF) Cb[cidx] = f2bf(v);
        else Cf[cidx] = v;
      }
    }
  }
}

extern "C" void kernel_launch(void* const* d_in, const int* in_sizes, int n_in,
                              void* d_out, int out_size, void* d_ws, size_t ws_size,
                              hipStream_t stream) {
  const float* x      = (const float*)d_in[0];
  const float* ln1_w  = (const float*)d_in[1];
  const float* ln1_b  = (const float*)d_in[2];
  const float* qkv_w  = (const float*)d_in[3];
  const float* qkv_b  = (const float*)d_in[4];
  const float* Ek     = (const float*)d_in[5];
  const float* Ev     = (const float*)d_in[6];
  const float* proj_w = (const float*)d_in[7];
  const float* proj_b = (const float*)d_in[8];
  const float* ln2_w  = (const float*)d_in[9];
  const float* ln2_b  = (const float*)d_in[10];
  const float* fc1_w  = (const float*)d_in[11];
  const float* fc1_b  = (const float*)d_in[12];
  const float* fc2_w  = (const float*)d_in[13];
  const float* fc2_b  = (const float*)d_in[14];
  float* out = (float*)d_out;

  // workspace carve-up (~251 MB total)
  char* w8 = (char*)d_ws;
  size_t off = 0;
  auto take = [&](size_t bytes) { char* p = w8 + off; off += bytes; return p; };
  uint16_t* qkv_wT  = (uint16_t*)take(2304ull * 768 * 2);   // [2304,768]
  uint16_t* proj_wT = (uint16_t*)take(768ull * 768 * 2);    // [768,768]
  uint16_t* fc1_wT  = (uint16_t*)take(3072ull * 768 * 2);   // [3072,768]
  uint16_t* fc2_wT  = (uint16_t*)take(768ull * 3072 * 2);   // [768,3072]
  uint16_t* EkT     = (uint16_t*)take(256ull * 8192 * 2);   // [256,8192]
  uint16_t* EvT     = (uint16_t*)take(256ull * 8192 * 2);   // must follow EkT
  uint16_t* h_bf    = (uint16_t*)take(16384ull * 768 * 2);  // LN out (reused for LN2)
  uint16_t* qkv_bf  = (uint16_t*)take(16384ull * 2304 * 2); // qkv
  uint16_t* big     = (uint16_t*)take(100663296ull);        // kvT -> logits -> a1
  uint16_t* kproj   = (uint16_t*)take(2ull * 2 * 256 * 768 * 2); // [kv][b][256][768]
  uint16_t* vprojT  = (uint16_t*)take(2ull * 768 * 256 * 2);     // [b][768][256]
  uint16_t* o_bf    = (uint16_t*)take(16384ull * 768 * 2);
  (void)ws_size; (void)in_sizes; (void)n_in; (void)out_size;

  const dim3 tb(32, 8);
  // 1) weights / projections -> bf16, transposed (so every GEMM is NT)
  transpose_f2b<<<dim3(72, 24), tb, 0, stream>>>(qkv_w, qkv_wT, 2304, 768);
  transpose_f2b<<<dim3(24, 24), tb, 0, stream>>>(proj_w, proj_wT, 768, 768);
  transpose_f2b<<<dim3(96, 24), tb, 0, stream>>>(fc1_w, fc1_wT, 3072, 768);
  transpose_f2b<<<dim3(24, 96), tb, 0, stream>>>(fc2_w, fc2_wT, 768, 3072);
  transpose_f2b<<<dim3(8, 256), tb, 0, stream>>>(Ek, EkT, 256, 8192);
  transpose_f2b<<<dim3(8, 256), tb, 0, stream>>>(Ev, EvT, 256, 8192);
  // 2) LN1
  ln768<<<16384, 256, 0, stream>>>(x, ln1_w, ln1_b, h_bf);
  // 3) qkv = h @ qkv_w + b   [16384,768]x[768,2304]
  gemm_nt<128, 128, true, true, false, false><<<dim3(128, 18, 1), 256, 0, stream>>>(
      h_bf, qkv_wT, qkv_bf, qkv_b, nullptr, 768, 768, 768, 2304, 1, 0, 0, 0, 0, 0, 0);
  // 4) transpose k,v slices -> kvT [kv][b][768][8192]
  uint16_t* kvT = big;
  for (int b = 0; b < 2; ++b) {
    transpose_b2b<<<dim3(24, 256), tb, 0, stream>>>(
        qkv_bf + (size_t)b * 8192 * 2304 + 768, kvT + (size_t)b * 768 * 8192, 2304, 8192);
    transpose_b2b<<<dim3(24, 256), tb, 0, stream>>>(
        qkv_bf + (size_t)b * 8192 * 2304 + 1536, kvT + (size_t)(2 + b) * 768 * 8192, 2304, 8192);
  }
  // 5) kv_proj[kv][b] = E{k,v}T [256,8192] @ kvT[kv][b] [768,8192]^T -> [256,768]
  gemm_nt<64, 64, true, false, false, false><<<dim3(4, 12, 4), 256, 0, stream>>>(
      EkT, kvT, kproj, nullptr, nullptr, 8192, 8192, 8192, 768,
      2, 256ull * 8192, 0, 2ull * 768 * 8192, 768ull * 8192, 2ull * 256 * 768, 256ull * 768);
  // 6) v_projT[b] [768,256]
  for (int b = 0; b < 2; ++b)
    transpose_b2b<<<dim3(24, 8), tb, 0, stream>>>(
        kproj + (size_t)(2 + b) * 256 * 768, vprojT + (size_t)b * 768 * 256, 768, 256);
  // 7) logits[b,h] = q[b,:,h] [8192,64] @ k_proj[b,h] [256,64]^T -> [8192,256]
  gemm_nt<128, 128, true, false, false, false><<<dim3(64, 2, 24), 256, 0, stream>>>(
      qkv_bf, kproj, big, nullptr, nullptr, 64, 2304, 768, 256,
      12, 8192ull * 2304, 64, 256ull * 768, 64, 12ull * 8192 * 256, 8192ull * 256);
  // 8) softmax rows (scale 1/8, clip +-50)
  softmax256<<<49152, 256, 0, stream>>>(big);
  // 9) o[b,h] = attn [8192,256] @ v_projT[b,h] [64,256]^T -> o_bf[n, h*64+d]
  gemm_nt<128, 64, true, false, false, false><<<dim3(64, 1, 24), 256, 0, stream>>>(
      big, vprojT, o_bf, nullptr, nullptr, 256, 256, 256, 768,
      12, 12ull * 8192 * 256, 8192ull * 256, 768ull * 256, 64ull * 256, 8192ull * 768, 64);
  // 10) x2 = x + o @ proj_w + b  -> d_out (fp32)
  gemm_nt<128, 128, false, true, false, true><<<dim3(128, 6, 1), 256, 0, stream>>>(
      o_bf, proj_wT, out, proj_b, x, 768, 768, 768, 768, 1, 0, 0, 0, 0, 0, 0);
  // 11) LN2 on x2
  ln768<<<16384, 256, 0, stream>>>(out, ln2_w, ln2_b, h_bf);
  // 12) a1 = gelu(h2 @ fc1_w + b)  [16384,768]x[768,3072]
  gemm_nt<128, 128, true, true, true, false><<<dim3(128, 24, 1), 256, 0, stream>>>(
      h_bf, fc1_wT, big, fc1_b, nullptr, 768, 768, 768, 3072, 1, 0, 0, 0, 0, 0, 0);
  // 13) out = x2 + a1 @ fc2_w + b  (in-place residual on d_out)
  gemm_nt<128, 128, false, true, false, true><<<dim3(128, 6, 1), 256, 0, stream>>>(
      big, fc2_wT, out, fc2_b, out, 3072, 3072, 3072, 768, 1, 0, 0, 0, 0, 0, 0);
}

// Round 2
// 685.674 us; speedup vs baseline: 1.1051x; 1.1051x over previous
//
#include <hip/hip_runtime.h>
#include <cstdint>

#define DEV __device__ __forceinline__

typedef __bf16 bf16x8 __attribute__((ext_vector_type(8)));
typedef float f32x4 __attribute__((ext_vector_type(4)));

DEV uint16_t f2bf(float f) {
  uint32_t u = __float_as_uint(f);
  u += 0x7FFFu + ((u >> 16) & 1u);
  return (uint16_t)(u >> 16);
}
DEV float bf2f(uint16_t h) { return __uint_as_float(((uint32_t)h) << 16); }

DEV void gload16(const void* g, void* l) {
  __builtin_amdgcn_global_load_lds((const __attribute__((address_space(1))) void*)g,
                                   (__attribute__((address_space(3))) void*)l, 16, 0, 0);
}

template <int N> DEV void waitcnt_vm() {
  if constexpr (N == 0) asm volatile("s_waitcnt vmcnt(0)" ::: "memory");
  else if constexpr (N == 3) asm volatile("s_waitcnt vmcnt(3)" ::: "memory");
  else if constexpr (N == 4) asm volatile("s_waitcnt vmcnt(4)" ::: "memory");
  else static_assert(N == 0 || N == 3 || N == 4, "unsupported vmcnt");
}

// ---------------- LayerNorm over C=768, fp32 in -> bf16 out ----------------
__global__ __launch_bounds__(256) void ln768(const float* __restrict__ x,
                                             const float* __restrict__ w,
                                             const float* __restrict__ b,
                                             uint16_t* __restrict__ out) {
  const size_t row = blockIdx.x;
  const float* xr = x + row * 768;
  const int t = threadIdx.x;
  float v0 = xr[t], v1 = xr[t + 256], v2 = xr[t + 512];
  float s = v0 + v1 + v2;
  float s2 = v0 * v0 + v1 * v1 + v2 * v2;
#pragma unroll
  for (int o = 32; o; o >>= 1) {
    s += __shfl_down(s, o);
    s2 += __shfl_down(s2, o);
  }
  __shared__ float sh[8];
  if ((t & 63) == 0) { sh[t >> 6] = s; sh[4 + (t >> 6)] = s2; }
  __syncthreads();
  s = sh[0] + sh[1] + sh[2] + sh[3];
  s2 = sh[4] + sh[5] + sh[6] + sh[7];
  const float mu = s * (1.f / 768.f);
  const float var = s2 * (1.f / 768.f) - mu * mu;
  const float rstd = rsqrtf(var + 1e-6f);
  uint16_t* orow = out + row * 768;
  orow[t]       = f2bf((v0 - mu) * rstd * w[t] + b[t]);
  orow[t + 256] = f2bf((v1 - mu) * rstd * w[t + 256] + b[t + 256]);
  orow[t + 512] = f2bf((v2 - mu) * rstd * w[t + 512] + b[t + 512]);
}

// ---------------- transpose fp32 [R,Cc] -> bf16 [Cc,R] ----------------
__global__ __launch_bounds__(256) void transpose_f2b(const float* __restrict__ in,
                                                     uint16_t* __restrict__ outp,
                                                     int ldin, int ldout) {
  __shared__ float tile[32][33];
  const int tx = threadIdx.x, ty = threadIdx.y;
  const size_t x = (size_t)blockIdx.x * 32 + tx;
  const size_t y = (size_t)blockIdx.y * 32 + ty;
#pragma unroll
  for (int j = 0; j < 4; ++j) tile[ty + j * 8][tx] = in[(y + j * 8) * ldin + x];
  __syncthreads();
  const size_t x2 = (size_t)blockIdx.y * 32 + tx;
  const size_t y2 = (size_t)blockIdx.x * 32 + ty;
#pragma unroll
  for (int j = 0; j < 4; ++j) outp[(y2 + j * 8) * ldout + x2] = f2bf(tile[tx][ty + j * 8]);
}

// ---------------- transpose bf16 [R,Cc] -> bf16 [Cc,R] ----------------
__global__ __launch_bounds__(256) void transpose_b2b(const uint16_t* __restrict__ in,
                                                     uint16_t* __restrict__ outp,
                                                     int ldin, int ldout) {
  __shared__ uint16_t tile[32][33];
  const int tx = threadIdx.x, ty = threadIdx.y;
  const size_t x = (size_t)blockIdx.x * 32 + tx;
  const size_t y = (size_t)blockIdx.y * 32 + ty;
#pragma unroll
  for (int j = 0; j < 4; ++j) tile[ty + j * 8][tx] = in[(y + j * 8) * ldin + x];
  __syncthreads();
  const size_t x2 = (size_t)blockIdx.y * 32 + tx;
  const size_t y2 = (size_t)blockIdx.x * 32 + ty;
#pragma unroll
  for (int j = 0; j < 4; ++j) outp[(y2 + j * 8) * ldout + x2] = tile[tx][ty + j * 8];
}

// ---------------- row softmax over 256 cols (bf16 in-place), scale+clip ----------------
__global__ __launch_bounds__(256) void softmax256(uint16_t* __restrict__ p) {
  const int wave = threadIdx.x >> 6, lane = threadIdx.x & 63;
  const size_t row = (size_t)blockIdx.x * 4 + wave;
  uint16_t* pr = p + row * 256 + lane * 4;
  ushort4 u = *(const ushort4*)pr;
  float f0 = bf2f(u.x) * 0.125f, f1 = bf2f(u.y) * 0.125f;
  float f2 = bf2f(u.z) * 0.125f, f3 = bf2f(u.w) * 0.125f;
  f0 = fminf(fmaxf(f0, -50.f), 50.f);
  f1 = fminf(fmaxf(f1, -50.f), 50.f);
  f2 = fminf(fmaxf(f2, -50.f), 50.f);
  f3 = fminf(fmaxf(f3, -50.f), 50.f);
  float m = fmaxf(fmaxf(f0, f1), fmaxf(f2, f3));
#pragma unroll
  for (int o = 32; o; o >>= 1) m = fmaxf(m, __shfl_xor(m, o));
  float e0 = __expf(f0 - m), e1 = __expf(f1 - m), e2 = __expf(f2 - m), e3 = __expf(f3 - m);
  float s = e0 + e1 + e2 + e3;
#pragma unroll
  for (int o = 32; o; o >>= 1) s += __shfl_xor(s, o);
  const float inv = 1.f / s;
  ushort4 o4;
  o4.x = f2bf(e0 * inv); o4.y = f2bf(e1 * inv);
  o4.z = f2bf(e2 * inv); o4.w = f2bf(e3 * inv);
  *(ushort4*)pr = o4;
}

// ---------------- legacy NT GEMM (kept for small attention GEMMs) ----------
template <int BM, int BN, bool OUTBF, bool HASBIAS, bool DOGELU, bool HASRES>
__global__ __launch_bounds__(256) void gemm_nt(
    const uint16_t* __restrict__ Abase, const uint16_t* __restrict__ Bbase,
    void* __restrict__ Cbase, const float* __restrict__ bias,
    const float* __restrict__ resbase, int Kd, int lda, int ldb, int ldc,
    int zdiv, size_t sAhi, size_t sAlo, size_t sBhi, size_t sBlo,
    size_t sChi, size_t sClo) {
  const int z = blockIdx.z;
  const int zhi = z / zdiv, zlo = z - zhi * zdiv;
  const uint16_t* A = Abase + zhi * sAhi + zlo * sAlo;
  const uint16_t* B = Bbase + zhi * sBhi + zlo * sBlo;
  const size_t coff = zhi * sChi + zlo * sClo;

  constexpr int WTM = BM / 2, WTN = BN / 2;
  constexpr int FM = WTM / 16, FN = WTN / 16;
  const int tid = threadIdx.x;
  const int wave = tid >> 6, lane = tid & 63;
  const int wm = wave >> 1, wn = wave & 1;
  const int l16 = lane & 15, lhi = lane >> 4;

  __shared__ __align__(16) uint16_t sA[BM * 32];
  __shared__ __align__(16) uint16_t sB[BN * 32];

  f32x4 acc[FM][FN];
#pragma unroll
  for (int m = 0; m < FM; ++m)
#pragma unroll
    for (int n = 0; n < FN; ++n) acc[m][n] = f32x4{0.f, 0.f, 0.f, 0.f};

  const int row0 = blockIdx.x * BM;
  const int col0 = blockIdx.y * BN;
  const int rr = tid >> 2, cq = tid & 3;

  for (int k0 = 0; k0 < Kd; k0 += 32) {
    __syncthreads();
#pragma unroll
    for (int is = 0; is < BM / 64; ++is) {
      const uint16_t* g = A + (size_t)(row0 + is * 64 + rr) * lda + k0 + cq * 8;
      gload16(g, &sA[is * 2048 + tid * 8]);
    }
#pragma unroll
    for (int is = 0; is < BN / 64; ++is) {
      const uint16_t* g = B + (size_t)(col0 + is * 64 + rr) * ldb + k0 + cq * 8;
      gload16(g, &sB[is * 2048 + tid * 8]);
    }
    __syncthreads();

    bf16x8 af[FM], bq[FN];
#pragma unroll
    for (int m = 0; m < FM; ++m)
      af[m] = *(const bf16x8*)(&sA[(wm * WTM + m * 16 + l16) * 32 + lhi * 8]);
#pragma unroll
    for (int n = 0; n < FN; ++n)
      bq[n] = *(const bf16x8*)(&sB[(wn * WTN + n * 16 + l16) * 32 + lhi * 8]);
#pragma unroll
    for (int m = 0; m < FM; ++m)
#pragma unroll
      for (int n = 0; n < FN; ++n)
        acc[m][n] = __builtin_amdgcn_mfma_f32_16x16x32_bf16(af[m], bq[n], acc[m][n], 0, 0, 0);
  }

  float* Cf = (float*)Cbase;
  uint16_t* Cb = (uint16_t*)Cbase;
#pragma unroll
  for (int m = 0; m < FM; ++m) {
#pragma unroll
    for (int n = 0; n < FN; ++n) {
      const int col = col0 + wn * WTN + n * 16 + l16;
      float bv = 0.f;
      if (HASBIAS) bv = bias[col];
#pragma unroll
      for (int r = 0; r < 4; ++r) {
        const int row = row0 + wm * WTM + m * 16 + lhi * 4 + r;
        float v = acc[m][n][r];
        if (HASBIAS) v += bv;
        if (DOGELU) v = 0.5f * v * (1.f + erff(v * 0.70710678118654752f));
        const size_t cidx = coff + (size_t)row * ldc + col;
        if (HASRES) v += resbase[cidx];
        if (OUTBF) Cb[cidx] = f2bf(v);
        else Cf[cidx] = v;
      }
    }
  }
}

// ======== 256-wide 8-wave pipelined NT GEMM: C[M,N] = A[M,K] @ B[N,K]^T ========
// BM=256 fixed. 3 LDS K-tile buffers (BK=32), prefetch 2 tiles ahead, counted
// vmcnt (never 0 in main loop), one raw s_barrier per K-tile, swizzled LDS
// (slot ^= (row>>1)&3 -> 2-way bank conflicts = free), setprio around MFMA,
// bijective XCD-aware block swizzle.
template <int BN, int WGN, bool OUTBF, bool HASBIAS, bool DOGELU, bool HASRES>
__global__ __launch_bounds__(512, 2) void gemm8(
    const uint16_t* __restrict__ A, const uint16_t* __restrict__ B,
    void* __restrict__ Cbase, const float* __restrict__ bias,
    const float* __restrict__ res, int Kd, int lda, int ldb, int ldc) {
  constexpr int WGM = 8 / WGN;
  constexpr int WROWS = 256 / WGM, WCOLS = BN / WGN;
  constexpr int FM = WROWS / 16, FN = WCOLS / 16;
  constexpr int LPT_B = BN / 128, LPT = 2 + LPT_B;
  constexpr int ABUF = 256 * 32, BBUF = BN * 32;  // elements per buffer
  __shared__ __align__(16) uint16_t lds[3 * (ABUF + BBUF)];

  // bijective XCD swizzle (m204 variant); consecutive wg share the B panel.
  const int gridM = gridDim.x;
  const int nwg = gridDim.x * gridDim.y;
  const int bid = blockIdx.y * gridDim.x + blockIdx.x;
  const int q = nwg >> 3, r8 = nwg & 7, xcd = bid & 7, idx = bid >> 3;
  const int wg = (xcd < r8 ? xcd * (q + 1) : r8 * (q + 1) + (xcd - r8) * q) + idx;
  const int bm = wg % gridM, bn = wg / gridM;
  const int row0 = bm * 256, col0 = bn * BN;

  const int tid = threadIdx.x;
  const int wave = tid >> 6, lane = tid & 63;
  const int wm = wave / WGN, wn = wave % WGN;
  const int l16 = lane & 15, lhi = lane >> 4;
  const int srow = tid >> 2, sslot = tid & 3;

  auto stage = [&](int buf, int t) {
    const int k0 = t * 32;
    uint16_t* sa = lds + buf * (ABUF + BBUF);
    uint16_t* sb = sa + ABUF;
#pragma unroll
    for (int j = 0; j < 2; ++j) {
      const int rw = j * 128 + srow;
      const int sp = sslot ^ ((rw >> 1) & 3);
      gload16(A + (size_t)(row0 + rw) * lda + k0 + sp * 8, sa + rw * 32 + sslot * 8);
    }
#pragma unroll
    for (int j = 0; j < LPT_B; ++j) {
      const int rw = j * 128 + srow;
      const int sp = sslot ^ ((rw >> 1) & 3);
      gload16(B + (size_t)(col0 + rw) * ldb + k0 + sp * 8, sb + rw * 32 + sslot * 8);
    }
  };

  f32x4 acc[FM][FN];
#pragma unroll
  for (int m = 0; m < FM; ++m)
#pragma unroll
    for (int n = 0; n < FN; ++n) acc[m][n] = f32x4{0.f, 0.f, 0.f, 0.f};

  const int NT = Kd >> 5;  // BK = 32; NT >= 3 for all our shapes
  stage(0, 0);
  stage(1, 1);

  for (int t = 0; t < NT; ++t) {
    if (t < NT - 1) waitcnt_vm<LPT>();  // tile t certified landed; t+1 stays in flight
    else waitcnt_vm<0>();               // epilogue drain
    __builtin_amdgcn_s_barrier();
    asm volatile("" ::: "memory");
    if (t + 2 < NT) stage((t + 2) % 3, t + 2);

    const uint16_t* sa = lds + (t % 3) * (ABUF + BBUF);
    const uint16_t* sb = sa + ABUF;
    bf16x8 af[FM], bf[FN];
#pragma unroll
    for (int n = 0; n < FN; ++n) {
      const int rw = wn * WCOLS + n * 16 + l16;
      bf[n] = *(const bf16x8*)(sb + rw * 32 + (lhi ^ ((rw >> 1) & 3)) * 8);
    }
#pragma unroll
    for (int m = 0; m < FM; ++m) {
      const int rw = wm * WROWS + m * 16 + l16;
      af[m] = *(const bf16x8*)(sa + rw * 32 + (lhi ^ ((rw >> 1) & 3)) * 8);
    }
    __builtin_amdgcn_s_setprio(1);
#pragma unroll
    for (int m = 0; m < FM; ++m)
#pragma unroll
      for (int n = 0; n < FN; ++n)
        acc[m][n] = __builtin_amdgcn_mfma_f32_16x16x32_bf16(af[m], bf[n], acc[m][n], 0, 0, 0);
    __builtin_amdgcn_s_setprio(0);
  }

  float* Cf = (float*)Cbase;
  uint16_t* Cb = (uint16_t*)Cbase;
#pragma unroll
  for (int m = 0; m < FM; ++m) {
#pragma unroll
    for (int n = 0; n < FN; ++n) {
      const int col = col0 + wn * WCOLS + n * 16 + l16;
      float bv = 0.f;
      if (HASBIAS) bv = bias[col];
#pragma unroll
      for (int r = 0; r < 4; ++r) {
        const int row = row0 + wm * WROWS + m * 16 + lhi * 4 + r;
        float v = acc[m][n][r] + bv;
        if (DOGELU) v = 0.5f * v * (1.f + erff(v * 0.70710678118654752f));
        const size_t cidx = (size_t)row * ldc + col;
        if (HASRES) v += res[cidx];
        if (OUTBF) Cb[cidx] = f2bf(v);
        else Cf[cidx] = v;
      }
    }
  }
}

extern "C" void kernel_launch(void* const* d_in, const int* in_sizes, int n_in,
                              void* d_out, int out_size, void* d_ws, size_t ws_size,
                              hipStream_t stream) {
  const float* x      = (const float*)d_in[0];
  const float* ln1_w  = (const float*)d_in[1];
  const float* ln1_b  = (const float*)d_in[2];
  const float* qkv_w  = (const float*)d_in[3];
  const float* qkv_b  = (const float*)d_in[4];
  const float* Ek     = (const float*)d_in[5];
  const float* Ev     = (const float*)d_in[6];
  const float* proj_w = (const float*)d_in[7];
  const float* proj_b = (const float*)d_in[8];
  const float* ln2_w  = (const float*)d_in[9];
  const float* ln2_b  = (const float*)d_in[10];
  const float* fc1_w  = (const float*)d_in[11];
  const float* fc1_b  = (const float*)d_in[12];
  const float* fc2_w  = (const float*)d_in[13];
  const float* fc2_b  = (const float*)d_in[14];
  float* out = (float*)d_out;

  char* w8 = (char*)d_ws;
  size_t off = 0;
  auto take = [&](size_t bytes) { char* p = w8 + off; off += bytes; return p; };
  uint16_t* qkv_wT  = (uint16_t*)take(2304ull * 768 * 2);
  uint16_t* proj_wT = (uint16_t*)take(768ull * 768 * 2);
  uint16_t* fc1_wT  = (uint16_t*)take(3072ull * 768 * 2);
  uint16_t* fc2_wT  = (uint16_t*)take(768ull * 3072 * 2);
  uint16_t* EkT     = (uint16_t*)take(256ull * 8192 * 2);
  uint16_t* EvT     = (uint16_t*)take(256ull * 8192 * 2);
  uint16_t* h_bf    = (uint16_t*)take(16384ull * 768 * 2);
  uint16_t* qkv_bf  = (uint16_t*)take(16384ull * 2304 * 2);
  uint16_t* big     = (uint16_t*)take(100663296ull);
  uint16_t* kproj   = (uint16_t*)take(2ull * 2 * 256 * 768 * 2);
  uint16_t* vprojT  = (uint16_t*)take(2ull * 768 * 256 * 2);
  uint16_t* o_bf    = (uint16_t*)take(16384ull * 768 * 2);
  (void)ws_size; (void)in_sizes; (void)n_in; (void)out_size;

  const dim3 tb(32, 8);
  // 1) weights -> bf16 transposed (all GEMMs NT)
  transpose_f2b<<<dim3(72, 24), tb, 0, stream>>>(qkv_w, qkv_wT, 2304, 768);
  transpose_f2b<<<dim3(24, 24), tb, 0, stream>>>(proj_w, proj_wT, 768, 768);
  transpose_f2b<<<dim3(96, 24), tb, 0, stream>>>(fc1_w, fc1_wT, 3072, 768);
  transpose_f2b<<<dim3(24, 96), tb, 0, stream>>>(fc2_w, fc2_wT, 768, 3072);
  transpose_f2b<<<dim3(8, 256), tb, 0, stream>>>(Ek, EkT, 256, 8192);
  transpose_f2b<<<dim3(8, 256), tb, 0, stream>>>(Ev, EvT, 256, 8192);
  // 2) LN1
  ln768<<<16384, 256, 0, stream>>>(x, ln1_w, ln1_b, h_bf);
  // 3) qkv = h @ qkv_w + b
  gemm8<256, 4, true, true, false, false><<<dim3(64, 9), 512, 0, stream>>>(
      h_bf, qkv_wT, qkv_bf, qkv_b, nullptr, 768, 768, 768, 2304);
  // 4) transpose k,v slices -> kvT [kv][b][768][8192]
  uint16_t* kvT = big;
  for (int b = 0; b < 2; ++b) {
    transpose_b2b<<<dim3(24, 256), tb, 0, stream>>>(
        qkv_bf + (size_t)b * 8192 * 2304 + 768, kvT + (size_t)b * 768 * 8192, 2304, 8192);
    transpose_b2b<<<dim3(24, 256), tb, 0, stream>>>(
        qkv_bf + (size_t)b * 8192 * 2304 + 1536, kvT + (size_t)(2 + b) * 768 * 8192, 2304, 8192);
  }
  // 5) kv_proj[kv][b] = E{k,v}T @ kvT^T -> [256,768]
  gemm_nt<64, 64, true, false, false, false><<<dim3(4, 12, 4), 256, 0, stream>>>(
      EkT, kvT, kproj, nullptr, nullptr, 8192, 8192, 8192, 768,
      2, 256ull * 8192, 0, 2ull * 768 * 8192, 768ull * 8192, 2ull * 256 * 768, 256ull * 768);
  // 6) v_projT[b] [768,256]
  for (int b = 0; b < 2; ++b)
    transpose_b2b<<<dim3(24, 8), tb, 0, stream>>>(
        kproj + (size_t)(2 + b) * 256 * 768, vprojT + (size_t)b * 768 * 256, 768, 256);
  // 7) logits[b,h] = q @ k_proj^T -> [8192,256]
  gemm_nt<128, 128, true, false, false, false><<<dim3(64, 2, 24), 256, 0, stream>>>(
      qkv_bf, kproj, big, nullptr, nullptr, 64, 2304, 768, 256,
      12, 8192ull * 2304, 64, 256ull * 768, 64, 12ull * 8192 * 256, 8192ull * 256);
  // 8) softmax
  softmax256<<<49152, 256, 0, stream>>>(big);
  // 9) o[b,h] = attn @ v_projT^T
  gemm_nt<128, 64, true, false, false, false><<<dim3(64, 1, 24), 256, 0, stream>>>(
      big, vprojT, o_bf, nullptr, nullptr, 256, 256, 256, 768,
      12, 12ull * 8192 * 256, 8192ull * 256, 768ull * 256, 64ull * 256, 8192ull * 768, 64);
  // 10) x2 = x + o @ proj_w + b -> d_out (fp32)
  gemm8<128, 2, false, true, false, true><<<dim3(64, 6), 512, 0, stream>>>(
      o_bf, proj_wT, out, proj_b, x, 768, 768, 768, 768);
  // 11) LN2
  ln768<<<16384, 256, 0, stream>>>(out, ln2_w, ln2_b, h_bf);
  // 12) a1 = gelu(h2 @ fc1_w + b)
  gemm8<256, 4, true, true, true, false><<<dim3(64, 12), 512, 0, stream>>>(
      h_bf, fc1_wT, big, fc1_b, nullptr, 768, 768, 768, 3072);
  // 13) out = x2 + a1 @ fc2_w + b (in-place residual)
  gemm8<128, 2, false, true, false, true><<<dim3(64, 6), 512, 0, stream>>>(
      big, fc2_wT, out, fc2_b, out, 3072, 3072, 3072, 768);
}

// Round 3
// 534.430 us; speedup vs baseline: 1.4178x; 1.2830x over previous
//
#include <hip/hip_runtime.h>
#include <cstdint>

#define DEV __device__ __forceinline__

typedef __bf16 bf16x8 __attribute__((ext_vector_type(8)));
typedef float f32x4 __attribute__((ext_vector_type(4)));

DEV uint16_t f2bf(float f) {
  uint32_t u = __float_as_uint(f);
  u += 0x7FFFu + ((u >> 16) & 1u);
  return (uint16_t)(u >> 16);
}
DEV float bf2f(uint16_t h) { return __uint_as_float(((uint32_t)h) << 16); }

DEV void gload16(const void* g, void* l) {
  __builtin_amdgcn_global_load_lds((const __attribute__((address_space(1))) void*)g,
                                   (__attribute__((address_space(3))) void*)l, 16, 0, 0);
}

template <int N> DEV void waitcnt_vm() {
  if constexpr (N == 0) asm volatile("s_waitcnt vmcnt(0)" ::: "memory");
  else if constexpr (N == 3) asm volatile("s_waitcnt vmcnt(3)" ::: "memory");
  else if constexpr (N == 4) asm volatile("s_waitcnt vmcnt(4)" ::: "memory");
  else static_assert(N == 0 || N == 3 || N == 4, "unsupported vmcnt");
}

// ---------------- LayerNorm over C=768, fp32 in -> bf16 out ----------------
__global__ __launch_bounds__(256) void ln768(const float* __restrict__ x,
                                             const float* __restrict__ w,
                                             const float* __restrict__ b,
                                             uint16_t* __restrict__ out) {
  const size_t row = blockIdx.x;
  const float* xr = x + row * 768;
  const int t = threadIdx.x;
  float v0 = xr[t], v1 = xr[t + 256], v2 = xr[t + 512];
  float s = v0 + v1 + v2;
  float s2 = v0 * v0 + v1 * v1 + v2 * v2;
#pragma unroll
  for (int o = 32; o; o >>= 1) {
    s += __shfl_down(s, o);
    s2 += __shfl_down(s2, o);
  }
  __shared__ float sh[8];
  if ((t & 63) == 0) { sh[t >> 6] = s; sh[4 + (t >> 6)] = s2; }
  __syncthreads();
  s = sh[0] + sh[1] + sh[2] + sh[3];
  s2 = sh[4] + sh[5] + sh[6] + sh[7];
  const float mu = s * (1.f / 768.f);
  const float var = s2 * (1.f / 768.f) - mu * mu;
  const float rstd = rsqrtf(var + 1e-6f);
  uint16_t* orow = out + row * 768;
  orow[t]       = f2bf((v0 - mu) * rstd * w[t] + b[t]);
  orow[t + 256] = f2bf((v1 - mu) * rstd * w[t + 256] + b[t + 256]);
  orow[t + 512] = f2bf((v2 - mu) * rstd * w[t + 512] + b[t + 512]);
}

// ---------------- transpose fp32 [R,Cc] -> bf16 [Cc,R] ----------------
__global__ __launch_bounds__(256) void transpose_f2b(const float* __restrict__ in,
                                                     uint16_t* __restrict__ outp,
                                                     int ldin, int ldout) {
  __shared__ float tile[32][33];
  const int tx = threadIdx.x, ty = threadIdx.y;
  const size_t x = (size_t)blockIdx.x * 32 + tx;
  const size_t y = (size_t)blockIdx.y * 32 + ty;
#pragma unroll
  for (int j = 0; j < 4; ++j) tile[ty + j * 8][tx] = in[(y + j * 8) * ldin + x];
  __syncthreads();
  const size_t x2 = (size_t)blockIdx.y * 32 + tx;
  const size_t y2 = (size_t)blockIdx.x * 32 + ty;
#pragma unroll
  for (int j = 0; j < 4; ++j) outp[(y2 + j * 8) * ldout + x2] = f2bf(tile[tx][ty + j * 8]);
}

// ---------------- transpose bf16 [R,Cc] -> bf16 [Cc,R] ----------------
__global__ __launch_bounds__(256) void transpose_b2b(const uint16_t* __restrict__ in,
                                                     uint16_t* __restrict__ outp,
                                                     int ldin, int ldout) {
  __shared__ uint16_t tile[32][33];
  const int tx = threadIdx.x, ty = threadIdx.y;
  const size_t x = (size_t)blockIdx.x * 32 + tx;
  const size_t y = (size_t)blockIdx.y * 32 + ty;
#pragma unroll
  for (int j = 0; j < 4; ++j) tile[ty + j * 8][tx] = in[(y + j * 8) * ldin + x];
  __syncthreads();
  const size_t x2 = (size_t)blockIdx.y * 32 + tx;
  const size_t y2 = (size_t)blockIdx.x * 32 + ty;
#pragma unroll
  for (int j = 0; j < 4; ++j) outp[(y2 + j * 8) * ldout + x2] = tile[tx][ty + j * 8];
}

// ---------------- legacy NT GEMM (used for split-K kv_proj partials) --------
template <int BM, int BN, bool OUTBF, bool HASBIAS, bool DOGELU, bool HASRES>
__global__ __launch_bounds__(256) void gemm_nt(
    const uint16_t* __restrict__ Abase, const uint16_t* __restrict__ Bbase,
    void* __restrict__ Cbase, const float* __restrict__ bias,
    const float* __restrict__ resbase, int Kd, int lda, int ldb, int ldc,
    int zdiv, size_t sAhi, size_t sAlo, size_t sBhi, size_t sBlo,
    size_t sChi, size_t sClo) {
  const int z = blockIdx.z;
  const int zhi = z / zdiv, zlo = z - zhi * zdiv;
  const uint16_t* A = Abase + zhi * sAhi + zlo * sAlo;
  const uint16_t* B = Bbase + zhi * sBhi + zlo * sBlo;
  const size_t coff = zhi * sChi + zlo * sClo;

  constexpr int WTM = BM / 2, WTN = BN / 2;
  constexpr int FM = WTM / 16, FN = WTN / 16;
  const int tid = threadIdx.x;
  const int wave = tid >> 6, lane = tid & 63;
  const int wm = wave >> 1, wn = wave & 1;
  const int l16 = lane & 15, lhi = lane >> 4;

  __shared__ __align__(16) uint16_t sA[BM * 32];
  __shared__ __align__(16) uint16_t sB[BN * 32];

  f32x4 acc[FM][FN];
#pragma unroll
  for (int m = 0; m < FM; ++m)
#pragma unroll
    for (int n = 0; n < FN; ++n) acc[m][n] = f32x4{0.f, 0.f, 0.f, 0.f};

  const int row0 = blockIdx.x * BM;
  const int col0 = blockIdx.y * BN;
  const int rr = tid >> 2, cq = tid & 3;

  for (int k0 = 0; k0 < Kd; k0 += 32) {
    __syncthreads();
#pragma unroll
    for (int is = 0; is < BM / 64; ++is) {
      const uint16_t* g = A + (size_t)(row0 + is * 64 + rr) * lda + k0 + cq * 8;
      gload16(g, &sA[is * 2048 + tid * 8]);
    }
#pragma unroll
    for (int is = 0; is < BN / 64; ++is) {
      const uint16_t* g = B + (size_t)(col0 + is * 64 + rr) * ldb + k0 + cq * 8;
      gload16(g, &sB[is * 2048 + tid * 8]);
    }
    __syncthreads();

    bf16x8 af[FM], bq[FN];
#pragma unroll
    for (int m = 0; m < FM; ++m)
      af[m] = *(const bf16x8*)(&sA[(wm * WTM + m * 16 + l16) * 32 + lhi * 8]);
#pragma unroll
    for (int n = 0; n < FN; ++n)
      bq[n] = *(const bf16x8*)(&sB[(wn * WTN + n * 16 + l16) * 32 + lhi * 8]);
#pragma unroll
    for (int m = 0; m < FM; ++m)
#pragma unroll
      for (int n = 0; n < FN; ++n)
        acc[m][n] = __builtin_amdgcn_mfma_f32_16x16x32_bf16(af[m], bq[n], acc[m][n], 0, 0, 0);
  }

  float* Cf = (float*)Cbase;
  uint16_t* Cb = (uint16_t*)Cbase;
#pragma unroll
  for (int m = 0; m < FM; ++m) {
#pragma unroll
    for (int n = 0; n < FN; ++n) {
      const int col = col0 + wn * WTN + n * 16 + l16;
      float bv = 0.f;
      if (HASBIAS) bv = bias[col];
#pragma unroll
      for (int r = 0; r < 4; ++r) {
        const int row = row0 + wm * WTM + m * 16 + lhi * 4 + r;
        float v = acc[m][n][r];
        if (HASBIAS) v += bv;
        if (DOGELU) v = 0.5f * v * (1.f + erff(v * 0.70710678118654752f));
        const size_t cidx = coff + (size_t)row * ldc + col;
        if (HASRES) v += resbase[cidx];
        if (OUTBF) Cb[cidx] = f2bf(v);
        else Cf[cidx] = v;
      }
    }
  }
}

// -------- kv_proj split-K reduce: sum 8 fp32 partials -> bf16; also emit vprojT
__global__ __launch_bounds__(256) void kv_reduce(const float* __restrict__ part,
                                                 uint16_t* __restrict__ kproj,
                                                 uint16_t* __restrict__ vprojT) {
  const int kvb = blockIdx.y;  // 0,1 = k(b=0,1); 2,3 = v(b=0,1)
  const int i = blockIdx.x * 256 + threadIdx.x;  // 0..196607
  const float* p = part + (size_t)kvb * 8 * 196608 + i;
  float s = 0.f;
#pragma unroll
  for (int j = 0; j < 8; ++j) s += p[(size_t)j * 196608];
  const uint16_t v = f2bf(s);
  kproj[(size_t)kvb * 196608 + i] = v;
  if (kvb >= 2) {
    const int b = kvb - 2, k = i / 768, c = i % 768;
    vprojT[((size_t)(b * 768 + c)) * 256 + k] = v;
  }
}

// ======== fused attention: logits -> softmax -> PV for one (qtile64, b, h) ====
// S^T = mfma(K, Q): lanes own contiguous kv per q-column; softmax over kv via
// shfl + small LDS; unnormalized P (bf16) -> swizzled LDS; PV with 1/sum folded
// into epilogue. K/Q/V fragments read directly from global (L2-resident).
__global__ __launch_bounds__(256, 3) void attn_fused(
    const uint16_t* __restrict__ qkv,    // [2][8192][2304]
    const uint16_t* __restrict__ kproj,  // [4][256][768] (kvb-major, kv=0 slices used)
    const uint16_t* __restrict__ vprojT, // [2][768][256]
    uint16_t* __restrict__ o) {          // [2][8192][768]
  const int bh = blockIdx.y;  // 0..23
  const int b = bh / 12, h = bh % 12;
  const int n0 = blockIdx.x * 64;
  const int tid = threadIdx.x, wave = tid >> 6, lane = tid & 63;
  const int l16 = lane & 15, lhi = lane >> 4;
  const int wm = wave >> 1, wn = wave & 1;

  __shared__ __align__(16) uint16_t sP[64 * 256];  // [n][kv], rows XOR-swizzled
  __shared__ float redm[2][64], reds[2][64], recs[64];

  const uint16_t* Kp = kproj + (size_t)b * 196608 + h * 64;        // row kv, ld 768
  const uint16_t* Qp = qkv + ((size_t)b * 8192 + n0) * 2304 + h * 64;  // row n, ld 2304
  const uint16_t* Vp = vprojT + ((size_t)b * 768 + h * 64) * 256;  // row d, ld 256

  // ---- S^T[kv=256][n=64]: waves 2x2, per-wave 128kv x 32n ----
  f32x4 st[8][2];
#pragma unroll
  for (int m = 0; m < 8; ++m)
#pragma unroll
    for (int nf = 0; nf < 2; ++nf) st[m][nf] = f32x4{0.f, 0.f, 0.f, 0.f};
#pragma unroll
  for (int ks = 0; ks < 2; ++ks) {
    bf16x8 kf[8], qf[2];
#pragma unroll
    for (int m = 0; m < 8; ++m) {
      const int kv = wm * 128 + m * 16 + l16;
      kf[m] = *(const bf16x8*)(Kp + (size_t)kv * 768 + ks * 32 + lhi * 8);
    }
#pragma unroll
    for (int nf = 0; nf < 2; ++nf) {
      const int n = wn * 32 + nf * 16 + l16;
      qf[nf] = *(const bf16x8*)(Qp + (size_t)n * 2304 + ks * 32 + lhi * 8);
    }
#pragma unroll
    for (int m = 0; m < 8; ++m)
#pragma unroll
      for (int nf = 0; nf < 2; ++nf)
        st[m][nf] = __builtin_amdgcn_mfma_f32_16x16x32_bf16(kf[m], qf[nf], st[m][nf], 0, 0, 0);
  }

  // scale + clip in place; per-column (n) max over kv
  float pmax[2] = {-50.f, -50.f};
#pragma unroll
  for (int m = 0; m < 8; ++m)
#pragma unroll
    for (int nf = 0; nf < 2; ++nf)
#pragma unroll
      for (int r = 0; r < 4; ++r) {
        float v = fminf(fmaxf(st[m][nf][r] * 0.125f, -50.f), 50.f);
        st[m][nf][r] = v;
        pmax[nf] = fmaxf(pmax[nf], v);
      }
#pragma unroll
  for (int nf = 0; nf < 2; ++nf) {
    pmax[nf] = fmaxf(pmax[nf], __shfl_xor(pmax[nf], 16));
    pmax[nf] = fmaxf(pmax[nf], __shfl_xor(pmax[nf], 32));
  }
  if (lhi == 0) {
#pragma unroll
    for (int nf = 0; nf < 2; ++nf) redm[wm][wn * 32 + nf * 16 + l16] = pmax[nf];
  }
  __syncthreads();
  float M[2];
#pragma unroll
  for (int nf = 0; nf < 2; ++nf) {
    const int col = wn * 32 + nf * 16 + l16;
    M[nf] = fmaxf(redm[0][col], redm[1][col]);
  }

  // exp, accumulate sum, pack unnormalized P -> sP
  float psum[2] = {0.f, 0.f};
#pragma unroll
  for (int m = 0; m < 8; ++m) {
#pragma unroll
    for (int nf = 0; nf < 2; ++nf) {
      float e0 = __expf(st[m][nf][0] - M[nf]);
      float e1 = __expf(st[m][nf][1] - M[nf]);
      float e2 = __expf(st[m][nf][2] - M[nf]);
      float e3 = __expf(st[m][nf][3] - M[nf]);
      psum[nf] += (e0 + e1) + (e2 + e3);
      uint2 pk;
      pk.x = (uint32_t)f2bf(e0) | ((uint32_t)f2bf(e1) << 16);
      pk.y = (uint32_t)f2bf(e2) | ((uint32_t)f2bf(e3) << 16);
      const int n = wn * 32 + nf * 16 + l16;
      const int kvb2 = (wm * 128 + m * 16 + lhi * 4) * 2;  // byte offset of kv
      *(uint2*)((char*)sP + n * 512 + (kvb2 ^ ((n & 7) << 4))) = pk;
    }
  }
#pragma unroll
  for (int nf = 0; nf < 2; ++nf) {
    psum[nf] += __shfl_xor(psum[nf], 16);
    psum[nf] += __shfl_xor(psum[nf], 32);
  }
  if (lhi == 0) {
#pragma unroll
    for (int nf = 0; nf < 2; ++nf) reds[wm][wn * 32 + nf * 16 + l16] = psum[nf];
  }
  __syncthreads();  // publishes sP and reds
  if (wm == 0 && lhi == 0) {
#pragma unroll
    for (int nf = 0; nf < 2; ++nf) {
      const int col = wn * 32 + nf * 16 + l16;
      recs[col] = 1.f / (reds[0][col] + reds[1][col]);
    }
  }
  __syncthreads();

  // ---- O[n=64][d=64] = P @ V^T : waves 2x2, per-wave 32n x 32d ----
  f32x4 pacc[2][2];
#pragma unroll
  for (int mf = 0; mf < 2; ++mf)
#pragma unroll
    for (int nf = 0; nf < 2; ++nf) pacc[mf][nf] = f32x4{0.f, 0.f, 0.f, 0.f};
#pragma unroll
  for (int ks = 0; ks < 8; ++ks) {
    bf16x8 pa[2], vb[2];
#pragma unroll
    for (int mf = 0; mf < 2; ++mf) {
      const int n = wm * 32 + mf * 16 + l16;
      pa[mf] = *(const bf16x8*)((char*)sP + n * 512 + ((ks * 64 + lhi * 16) ^ ((n & 7) << 4)));
    }
#pragma unroll
    for (int nf = 0; nf < 2; ++nf) {
      const int d = wn * 32 + nf * 16 + l16;
      vb[nf] = *(const bf16x8*)(Vp + (size_t)d * 256 + ks * 32 + lhi * 8);
    }
#pragma unroll
    for (int mf = 0; mf < 2; ++mf)
#pragma unroll
      for (int nf = 0; nf < 2; ++nf)
        pacc[mf][nf] = __builtin_amdgcn_mfma_f32_16x16x32_bf16(pa[mf], vb[nf], pacc[mf][nf], 0, 0, 0);
  }
  uint16_t* orow = o + ((size_t)b * 8192 + n0) * 768 + h * 64;
#pragma unroll
  for (int mf = 0; mf < 2; ++mf) {
#pragma unroll
    for (int r = 0; r < 4; ++r) {
      const int n = wm * 32 + mf * 16 + lhi * 4 + r;
      const float inv = recs[n];
#pragma unroll
      for (int nf = 0; nf < 2; ++nf) {
        const int d = wn * 32 + nf * 16 + l16;
        orow[(size_t)n * 768 + d] = f2bf(pacc[mf][nf][r] * inv);
      }
    }
  }
}

// ======== pipelined NT GEMM v2: 3 LDS buffers, 2-ahead prefetch, counted vmcnt,
// XOR-swizzled LDS, setprio, bijective XCD swizzle with bn-fastest chunks.
template <int BM, int BN, int NTHR, int WGN, bool OUTBF, bool HASBIAS, bool DOGELU, bool HASRES>
__global__ __launch_bounds__(NTHR, (NTHR == 512) ? 4 : 3) void gemm8v2(
    const uint16_t* __restrict__ A, const uint16_t* __restrict__ B,
    void* __restrict__ Cbase, const float* __restrict__ bias,
    const float* __restrict__ res, int Kd, int lda, int ldb, int ldc) {
  constexpr int NWAVES = NTHR / 64;
  constexpr int WGM = NWAVES / WGN;
  constexpr int WROWS = BM / WGM, WCOLS = BN / WGN;
  constexpr int FM = WROWS / 16, FN = WCOLS / 16;
  constexpr int RPI = NTHR / 4;              // rows staged per load inst
  constexpr int IA = BM / RPI, IB = BN / RPI;
  constexpr int LPT = IA + IB;
  constexpr int ABUF = BM * 32, BBUF = BN * 32;
  __shared__ __align__(16) uint16_t lds[3 * (ABUF + BBUF)];

  // bijective XCD swizzle; consecutive wg in a chunk share the A row-panel.
  const int nn = gridDim.y;
  const int nwg = gridDim.x * gridDim.y;
  const int bid = blockIdx.y * gridDim.x + blockIdx.x;
  const int q = nwg >> 3, r8 = nwg & 7, xcd = bid & 7, idx = bid >> 3;
  const int wg = (xcd < r8 ? xcd * (q + 1) : r8 * (q + 1) + (xcd - r8) * q) + idx;
  const int bm = wg / nn, bn = wg % nn;
  const int row0 = bm * BM, col0 = bn * BN;

  const int tid = threadIdx.x;
  const int wave = tid >> 6, lane = tid & 63;
  const int wm = wave / WGN, wn = wave % WGN;
  const int l16 = lane & 15, lhi = lane >> 4;
  const int srow = tid >> 2, sslot = tid & 3;

  auto stage = [&](int buf, int t) {
    const int k0 = t * 32;
    uint16_t* sa = lds + buf * (ABUF + BBUF);
    uint16_t* sb = sa + ABUF;
#pragma unroll
    for (int j = 0; j < IA; ++j) {
      const int rw = j * RPI + srow;
      const int sp = sslot ^ ((rw >> 1) & 3);
      gload16(A + (size_t)(row0 + rw) * lda + k0 + sp * 8, sa + rw * 32 + sslot * 8);
    }
#pragma unroll
    for (int j = 0; j < IB; ++j) {
      const int rw = j * RPI + srow;
      const int sp = sslot ^ ((rw >> 1) & 3);
      gload16(B + (size_t)(col0 + rw) * ldb + k0 + sp * 8, sb + rw * 32 + sslot * 8);
    }
  };

  f32x4 acc[FM][FN];
#pragma unroll
  for (int m = 0; m < FM; ++m)
#pragma unroll
    for (int n = 0; n < FN; ++n) acc[m][n] = f32x4{0.f, 0.f, 0.f, 0.f};

  const int NT = Kd >> 5;
  stage(0, 0);
  stage(1, 1);

  for (int t = 0; t < NT; ++t) {
    if (t < NT - 1) waitcnt_vm<LPT>();
    else waitcnt_vm<0>();
    __builtin_amdgcn_s_barrier();
    asm volatile("" ::: "memory");
    if (t + 2 < NT) stage((t + 2) % 3, t + 2);

    const uint16_t* sa = lds + (t % 3) * (ABUF + BBUF);
    const uint16_t* sb = sa + ABUF;
    bf16x8 af[FM], bf[FN];
#pragma unroll
    for (int n = 0; n < FN; ++n) {
      const int rw = wn * WCOLS + n * 16 + l16;
      bf[n] = *(const bf16x8*)(sb + rw * 32 + (lhi ^ ((rw >> 1) & 3)) * 8);
    }
#pragma unroll
    for (int m = 0; m < FM; ++m) {
      const int rw = wm * WROWS + m * 16 + l16;
      af[m] = *(const bf16x8*)(sa + rw * 32 + (lhi ^ ((rw >> 1) & 3)) * 8);
    }
    __builtin_amdgcn_s_setprio(1);
#pragma unroll
    for (int m = 0; m < FM; ++m)
#pragma unroll
      for (int n = 0; n < FN; ++n)
        acc[m][n] = __builtin_amdgcn_mfma_f32_16x16x32_bf16(af[m], bf[n], acc[m][n], 0, 0, 0);
    __builtin_amdgcn_s_setprio(0);
  }

  float* Cf = (float*)Cbase;
  uint16_t* Cb = (uint16_t*)Cbase;
#pragma unroll
  for (int m = 0; m < FM; ++m) {
#pragma unroll
    for (int n = 0; n < FN; ++n) {
      const int col = col0 + wn * WCOLS + n * 16 + l16;
      float bv = 0.f;
      if (HASBIAS) bv = bias[col];
#pragma unroll
      for (int r = 0; r < 4; ++r) {
        const int row = row0 + wm * WROWS + m * 16 + lhi * 4 + r;
        float v = acc[m][n][r] + bv;
        if (DOGELU) v = 0.5f * v * (1.f + erff(v * 0.70710678118654752f));
        const size_t cidx = (size_t)row * ldc + col;
        if (HASRES) v += res[cidx];
        if (OUTBF) Cb[cidx] = f2bf(v);
        else Cf[cidx] = v;
      }
    }
  }
}

extern "C" void kernel_launch(void* const* d_in, const int* in_sizes, int n_in,
                              void* d_out, int out_size, void* d_ws, size_t ws_size,
                              hipStream_t stream) {
  const float* x      = (const float*)d_in[0];
  const float* ln1_w  = (const float*)d_in[1];
  const float* ln1_b  = (const float*)d_in[2];
  const float* qkv_w  = (const float*)d_in[3];
  const float* qkv_b  = (const float*)d_in[4];
  const float* Ek     = (const float*)d_in[5];
  const float* Ev     = (const float*)d_in[6];
  const float* proj_w = (const float*)d_in[7];
  const float* proj_b = (const float*)d_in[8];
  const float* ln2_w  = (const float*)d_in[9];
  const float* ln2_b  = (const float*)d_in[10];
  const float* fc1_w  = (const float*)d_in[11];
  const float* fc1_b  = (const float*)d_in[12];
  const float* fc2_w  = (const float*)d_in[13];
  const float* fc2_b  = (const float*)d_in[14];
  float* out = (float*)d_out;

  char* w8 = (char*)d_ws;
  size_t off = 0;
  auto take = [&](size_t bytes) { char* p = w8 + off; off += bytes; return p; };
  uint16_t* qkv_wT  = (uint16_t*)take(2304ull * 768 * 2);
  uint16_t* proj_wT = (uint16_t*)take(768ull * 768 * 2);
  uint16_t* fc1_wT  = (uint16_t*)take(3072ull * 768 * 2);
  uint16_t* fc2_wT  = (uint16_t*)take(768ull * 3072 * 2);
  uint16_t* EkT     = (uint16_t*)take(256ull * 8192 * 2);
  uint16_t* EvT     = (uint16_t*)take(256ull * 8192 * 2);
  uint16_t* h_bf    = (uint16_t*)take(16384ull * 768 * 2);
  uint16_t* qkv_bf  = (uint16_t*)take(16384ull * 2304 * 2);
  uint16_t* big     = (uint16_t*)take(100663296ull);             // kvT -> fc1 out
  uint16_t* kproj   = (uint16_t*)take(2ull * 2 * 256 * 768 * 2); // [kvb][256][768]
  uint16_t* vprojT  = (uint16_t*)take(2ull * 768 * 256 * 2);     // [b][768][256]
  uint16_t* o_bf    = (uint16_t*)take(16384ull * 768 * 2);       // also kv_proj partials
  float* part = (float*)o_bf;  // 4*8*196608*4B == 25165824 == o_bf size
  (void)ws_size; (void)in_sizes; (void)n_in; (void)out_size;

  const dim3 tb(32, 8);
  // 1) weights -> bf16 transposed (all GEMMs NT)
  transpose_f2b<<<dim3(72, 24), tb, 0, stream>>>(qkv_w, qkv_wT, 2304, 768);
  transpose_f2b<<<dim3(24, 24), tb, 0, stream>>>(proj_w, proj_wT, 768, 768);
  transpose_f2b<<<dim3(96, 24), tb, 0, stream>>>(fc1_w, fc1_wT, 3072, 768);
  transpose_f2b<<<dim3(24, 96), tb, 0, stream>>>(fc2_w, fc2_wT, 768, 3072);
  transpose_f2b<<<dim3(8, 256), tb, 0, stream>>>(Ek, EkT, 256, 8192);
  transpose_f2b<<<dim3(8, 256), tb, 0, stream>>>(Ev, EvT, 256, 8192);
  // 2) LN1
  ln768<<<16384, 256, 0, stream>>>(x, ln1_w, ln1_b, h_bf);
  // 3) qkv = h @ qkv_w + b
  gemm8v2<256, 128, 512, 2, true, true, false, false><<<dim3(64, 18), 512, 0, stream>>>(
      h_bf, qkv_wT, qkv_bf, qkv_b, nullptr, 768, 768, 768, 2304);
  // 4) transpose k,v slices -> kvT [kvb][768][8192]
  uint16_t* kvT = big;
  for (int b = 0; b < 2; ++b) {
    transpose_b2b<<<dim3(24, 256), tb, 0, stream>>>(
        qkv_bf + (size_t)b * 8192 * 2304 + 768, kvT + (size_t)b * 768 * 8192, 2304, 8192);
    transpose_b2b<<<dim3(24, 256), tb, 0, stream>>>(
        qkv_bf + (size_t)b * 8192 * 2304 + 1536, kvT + (size_t)(2 + b) * 768 * 8192, 2304, 8192);
  }
  // 5) kv_proj split-K: 4 x (E^T [256,8192] @ kvT[kvb]^T), splitK=8 -> fp32 partials
  for (int kvb = 0; kvb < 4; ++kvb) {
    const uint16_t* Ab = (kvb < 2) ? EkT : EvT;
    gemm_nt<64, 64, false, false, false, false><<<dim3(4, 12, 8), 256, 0, stream>>>(
        Ab, kvT + (size_t)kvb * 768 * 8192, part + (size_t)kvb * 8 * 196608,
        nullptr, nullptr, 1024, 8192, 8192, 768,
        1, 1024, 0, 1024, 0, 196608, 0);
  }
  // 6) reduce partials -> kproj bf16 (+ vprojT for v slices)
  kv_reduce<<<dim3(768, 4), 256, 0, stream>>>(part, kproj, vprojT);
  // 7-9) fused attention -> o_bf
  attn_fused<<<dim3(128, 24), 256, 0, stream>>>(qkv_bf, kproj, vprojT, o_bf);
  // 10) x2 = x + o @ proj_w + b -> d_out (fp32)
  gemm8v2<128, 128, 256, 2, false, true, false, true><<<dim3(128, 6), 256, 0, stream>>>(
      o_bf, proj_wT, out, proj_b, x, 768, 768, 768, 768);
  // 11) LN2
  ln768<<<16384, 256, 0, stream>>>(out, ln2_w, ln2_b, h_bf);
  // 12) a1 = gelu(h2 @ fc1_w + b) -> big
  gemm8v2<256, 128, 512, 2, true, true, true, false><<<dim3(64, 24), 512, 0, stream>>>(
      h_bf, fc1_wT, big, fc1_b, nullptr, 768, 768, 768, 3072);
  // 13) out = x2 + a1 @ fc2_w + b (in-place residual)
  gemm8v2<128, 128, 256, 2, false, true, false, true><<<dim3(128, 6), 256, 0, stream>>>(
      big, fc2_wT, out, fc2_b, out, 3072, 3072, 3072, 768);
}

// Round 4
// 489.864 us; speedup vs baseline: 1.5468x; 1.0910x over previous
//
#include <hip/hip_runtime.h>
#include <cstdint>

#define DEV __device__ __forceinline__

typedef __bf16 bf16x8 __attribute__((ext_vector_type(8)));
typedef float f32x4 __attribute__((ext_vector_type(4)));

DEV uint16_t f2bf(float f) {
  uint32_t u = __float_as_uint(f);
  u += 0x7FFFu + ((u >> 16) & 1u);
  return (uint16_t)(u >> 16);
}
DEV float bf2f(uint16_t h) { return __uint_as_float(((uint32_t)h) << 16); }

DEV void gload16(const void* g, void* l) {
  __builtin_amdgcn_global_load_lds((const __attribute__((address_space(1))) void*)g,
                                   (__attribute__((address_space(3))) void*)l, 16, 0, 0);
}

template <int N> DEV void waitcnt_vm() {
  if constexpr (N == 0) asm volatile("s_waitcnt vmcnt(0)" ::: "memory");
  else if constexpr (N == 4) asm volatile("s_waitcnt vmcnt(4)" ::: "memory");
  else if constexpr (N == 6) asm volatile("s_waitcnt vmcnt(6)" ::: "memory");
  else static_assert(N == 0 || N == 4 || N == 6, "unsupported vmcnt");
}

// fast GELU (tanh/sigmoid form): max abs err vs erf-GELU ~3e-3
DEV float gelu_f(float v) {
  float u = v * (0.7978845608f + 0.0356774081f * v * v);  // sqrt(2/pi)*(v+0.044715 v^3)
  return v / (1.f + __expf(-2.f * u));
}

// ---------------- LayerNorm over C=768, fp32 in -> bf16 out ----------------
__global__ __launch_bounds__(256) void ln768(const float* __restrict__ x,
                                             const float* __restrict__ w,
                                             const float* __restrict__ b,
                                             uint16_t* __restrict__ out) {
  const size_t row = blockIdx.x;
  const float* xr = x + row * 768;
  const int t = threadIdx.x;
  float v0 = xr[t], v1 = xr[t + 256], v2 = xr[t + 512];
  float s = v0 + v1 + v2;
  float s2 = v0 * v0 + v1 * v1 + v2 * v2;
#pragma unroll
  for (int o = 32; o; o >>= 1) {
    s += __shfl_down(s, o);
    s2 += __shfl_down(s2, o);
  }
  __shared__ float sh[8];
  if ((t & 63) == 0) { sh[t >> 6] = s; sh[4 + (t >> 6)] = s2; }
  __syncthreads();
  s = sh[0] + sh[1] + sh[2] + sh[3];
  s2 = sh[4] + sh[5] + sh[6] + sh[7];
  const float mu = s * (1.f / 768.f);
  const float var = s2 * (1.f / 768.f) - mu * mu;
  const float rstd = rsqrtf(var + 1e-6f);
  uint16_t* orow = out + row * 768;
  orow[t]       = f2bf((v0 - mu) * rstd * w[t] + b[t]);
  orow[t + 256] = f2bf((v1 - mu) * rstd * w[t + 256] + b[t + 256]);
  orow[t + 512] = f2bf((v2 - mu) * rstd * w[t + 512] + b[t + 512]);
}

// ---------------- transpose fp32 [R,Cc] -> bf16 [Cc,R] ----------------
__global__ __launch_bounds__(256) void transpose_f2b(const float* __restrict__ in,
                                                     uint16_t* __restrict__ outp,
                                                     int ldin, int ldout) {
  __shared__ float tile[32][33];
  const int tx = threadIdx.x, ty = threadIdx.y;
  const size_t x = (size_t)blockIdx.x * 32 + tx;
  const size_t y = (size_t)blockIdx.y * 32 + ty;
#pragma unroll
  for (int j = 0; j < 4; ++j) tile[ty + j * 8][tx] = in[(y + j * 8) * ldin + x];
  __syncthreads();
  const size_t x2 = (size_t)blockIdx.y * 32 + tx;
  const size_t y2 = (size_t)blockIdx.x * 32 + ty;
#pragma unroll
  for (int j = 0; j < 4; ++j) outp[(y2 + j * 8) * ldout + x2] = f2bf(tile[tx][ty + j * 8]);
}

// ---------------- transpose bf16 [R,Cc] -> bf16 [Cc,R] ----------------
__global__ __launch_bounds__(256) void transpose_b2b(const uint16_t* __restrict__ in,
                                                     uint16_t* __restrict__ outp,
                                                     int ldin, int ldout) {
  __shared__ uint16_t tile[32][33];
  const int tx = threadIdx.x, ty = threadIdx.y;
  const size_t x = (size_t)blockIdx.x * 32 + tx;
  const size_t y = (size_t)blockIdx.y * 32 + ty;
#pragma unroll
  for (int j = 0; j < 4; ++j) tile[ty + j * 8][tx] = in[(y + j * 8) * ldin + x];
  __syncthreads();
  const size_t x2 = (size_t)blockIdx.y * 32 + tx;
  const size_t y2 = (size_t)blockIdx.x * 32 + ty;
#pragma unroll
  for (int j = 0; j < 4; ++j) outp[(y2 + j * 8) * ldout + x2] = tile[tx][ty + j * 8];
}

// ======== kv_proj TN with gather: part[ns][kvb][k][c] = sum_{n in stripe} E[k][n]*kv[n][c]
// E = EkT/EvT [256][8192] bf16; kv columns gathered from qkv_bf (16 lanes read
// 16 consecutive c at same n -> coalesced 32B segments). 768 blocks.
__global__ __launch_bounds__(256) void kv_tn(const uint16_t* __restrict__ EkT,
                                             const uint16_t* __restrict__ EvT,
                                             const uint16_t* __restrict__ qkv,
                                             float* __restrict__ part) {
  // XCD chunking: 96 consecutive wg per XCD share c-slabs across (kt, ns)
  const int bid = blockIdx.x;
  const int wg = (bid & 7) * 96 + (bid >> 3);
  const int inner = wg & 15;
  const int kt = inner & 3, ns = inner >> 2;
  const int rest = wg >> 4;
  const int ct = rest % 12, kvb = rest / 12;
  const int kv = kvb >> 1, b = kvb & 1;
  const int k0 = kt * 64, c0 = ct * 64, nsb = ns * 2048;

  const uint16_t* E = kv ? EvT : EkT;
  const uint16_t* KV = qkv + (size_t)b * 8192 * 2304 + 768 + kv * 768 + c0;
  const int tid = threadIdx.x, wave = tid >> 6, lane = tid & 63;
  const int l16 = lane & 15, lhi = lane >> 4;
  const int wm = wave >> 1, wn = wave & 1;

  f32x4 acc[2][2];
#pragma unroll
  for (int m = 0; m < 2; ++m)
#pragma unroll
    for (int n = 0; n < 2; ++n) acc[m][n] = f32x4{0.f, 0.f, 0.f, 0.f};

  const uint16_t* Eb = E + (size_t)(k0 + wm * 32 + l16) * 8192 + nsb + lhi * 8;
  const uint16_t* KVb = KV + ((size_t)nsb + lhi * 8) * 2304 + wn * 32 + l16;

  for (int n0 = 0; n0 < 2048; n0 += 32) {
    bf16x8 ef[2];
    ef[0] = *(const bf16x8*)(Eb + n0);
    ef[1] = *(const bf16x8*)(Eb + 16 * 8192 + n0);
    bf16x8 vf[2];
#pragma unroll
    for (int nf = 0; nf < 2; ++nf) {
      const uint16_t* p = KVb + (size_t)n0 * 2304 + nf * 16;
      union { bf16x8 v; uint16_t u[8]; } tu;
#pragma unroll
      for (int j = 0; j < 8; ++j) tu.u[j] = p[(size_t)j * 2304];
      vf[nf] = tu.v;
    }
#pragma unroll
    for (int m = 0; m < 2; ++m)
#pragma unroll
      for (int nf = 0; nf < 2; ++nf)
        acc[m][nf] = __builtin_amdgcn_mfma_f32_16x16x32_bf16(ef[m], vf[nf], acc[m][nf], 0, 0, 0);
  }

  float* outp = part + ((size_t)ns * 4 + kvb) * 196608;
#pragma unroll
  for (int m = 0; m < 2; ++m)
#pragma unroll
    for (int nf = 0; nf < 2; ++nf)
#pragma unroll
      for (int r = 0; r < 4; ++r)
        outp[(size_t)(k0 + wm * 32 + m * 16 + lhi * 4 + r) * 768 + c0 + wn * 32 + nf * 16 + l16] =
            acc[m][nf][r];
}

// -------- reduce 4 n-stripe partials -> bf16 kproj
__global__ __launch_bounds__(256) void kv_reduce(const float* __restrict__ part,
                                                 uint16_t* __restrict__ kproj) {
  const int kvb = blockIdx.y;
  const int i = blockIdx.x * 256 + threadIdx.x;
  const float* p = part + (size_t)kvb * 196608 + i;
  float s = p[0] + p[786432] + p[2 * 786432] + p[3 * 786432];
  kproj[(size_t)kvb * 196608 + i] = f2bf(s);
}

// ======== fused attention: logits -> softmax -> PV for one (qtile64, b, h) ====
__global__ __launch_bounds__(256, 3) void attn_fused(
    const uint16_t* __restrict__ qkv,    // [2][8192][2304]
    const uint16_t* __restrict__ kproj,  // [4][256][768]
    const uint16_t* __restrict__ vprojT, // [2][768][256]
    uint16_t* __restrict__ o) {          // [2][8192][768]
  const int bh = blockIdx.y;
  const int b = bh / 12, h = bh % 12;
  const int n0 = blockIdx.x * 64;
  const int tid = threadIdx.x, wave = tid >> 6, lane = tid & 63;
  const int l16 = lane & 15, lhi = lane >> 4;
  const int wm = wave >> 1, wn = wave & 1;

  __shared__ __align__(16) uint16_t sP[64 * 256];
  __shared__ float redm[2][64], reds[2][64], recs[64];

  const uint16_t* Kp = kproj + (size_t)b * 196608 + h * 64;
  const uint16_t* Qp = qkv + ((size_t)b * 8192 + n0) * 2304 + h * 64;
  const uint16_t* Vp = vprojT + ((size_t)b * 768 + h * 64) * 256;

  f32x4 st[8][2];
#pragma unroll
  for (int m = 0; m < 8; ++m)
#pragma unroll
    for (int nf = 0; nf < 2; ++nf) st[m][nf] = f32x4{0.f, 0.f, 0.f, 0.f};
#pragma unroll
  for (int ks = 0; ks < 2; ++ks) {
    bf16x8 kf[8], qf[2];
#pragma unroll
    for (int m = 0; m < 8; ++m) {
      const int kvi = wm * 128 + m * 16 + l16;
      kf[m] = *(const bf16x8*)(Kp + (size_t)kvi * 768 + ks * 32 + lhi * 8);
    }
#pragma unroll
    for (int nf = 0; nf < 2; ++nf) {
      const int n = wn * 32 + nf * 16 + l16;
      qf[nf] = *(const bf16x8*)(Qp + (size_t)n * 2304 + ks * 32 + lhi * 8);
    }
#pragma unroll
    for (int m = 0; m < 8; ++m)
#pragma unroll
      for (int nf = 0; nf < 2; ++nf)
        st[m][nf] = __builtin_amdgcn_mfma_f32_16x16x32_bf16(kf[m], qf[nf], st[m][nf], 0, 0, 0);
  }

  float pmax[2] = {-50.f, -50.f};
#pragma unroll
  for (int m = 0; m < 8; ++m)
#pragma unroll
    for (int nf = 0; nf < 2; ++nf)
#pragma unroll
      for (int r = 0; r < 4; ++r) {
        float v = fminf(fmaxf(st[m][nf][r] * 0.125f, -50.f), 50.f);
        st[m][nf][r] = v;
        pmax[nf] = fmaxf(pmax[nf], v);
      }
#pragma unroll
  for (int nf = 0; nf < 2; ++nf) {
    pmax[nf] = fmaxf(pmax[nf], __shfl_xor(pmax[nf], 16));
    pmax[nf] = fmaxf(pmax[nf], __shfl_xor(pmax[nf], 32));
  }
  if (lhi == 0) {
#pragma unroll
    for (int nf = 0; nf < 2; ++nf) redm[wm][wn * 32 + nf * 16 + l16] = pmax[nf];
  }
  __syncthreads();
  float M[2];
#pragma unroll
  for (int nf = 0; nf < 2; ++nf) {
    const int col = wn * 32 + nf * 16 + l16;
    M[nf] = fmaxf(redm[0][col], redm[1][col]);
  }

  float psum[2] = {0.f, 0.f};
#pragma unroll
  for (int m = 0; m < 8; ++m) {
#pragma unroll
    for (int nf = 0; nf < 2; ++nf) {
      float e0 = __expf(st[m][nf][0] - M[nf]);
      float e1 = __expf(st[m][nf][1] - M[nf]);
      float e2 = __expf(st[m][nf][2] - M[nf]);
      float e3 = __expf(st[m][nf][3] - M[nf]);
      psum[nf] += (e0 + e1) + (e2 + e3);
      uint2 pk;
      pk.x = (uint32_t)f2bf(e0) | ((uint32_t)f2bf(e1) << 16);
      pk.y = (uint32_t)f2bf(e2) | ((uint32_t)f2bf(e3) << 16);
      const int n = wn * 32 + nf * 16 + l16;
      const int kvb2 = (wm * 128 + m * 16 + lhi * 4) * 2;
      *(uint2*)((char*)sP + n * 512 + (kvb2 ^ ((n & 7) << 4))) = pk;
    }
  }
#pragma unroll
  for (int nf = 0; nf < 2; ++nf) {
    psum[nf] += __shfl_xor(psum[nf], 16);
    psum[nf] += __shfl_xor(psum[nf], 32);
  }
  if (lhi == 0) {
#pragma unroll
    for (int nf = 0; nf < 2; ++nf) reds[wm][wn * 32 + nf * 16 + l16] = psum[nf];
  }
  __syncthreads();
  if (wm == 0 && lhi == 0) {
#pragma unroll
    for (int nf = 0; nf < 2; ++nf) {
      const int col = wn * 32 + nf * 16 + l16;
      recs[col] = 1.f / (reds[0][col] + reds[1][col]);
    }
  }
  __syncthreads();

  f32x4 pacc[2][2];
#pragma unroll
  for (int mf = 0; mf < 2; ++mf)
#pragma unroll
    for (int nf = 0; nf < 2; ++nf) pacc[mf][nf] = f32x4{0.f, 0.f, 0.f, 0.f};
#pragma unroll
  for (int ks = 0; ks < 8; ++ks) {
    bf16x8 pa[2], vb[2];
#pragma unroll
    for (int mf = 0; mf < 2; ++mf) {
      const int n = wm * 32 + mf * 16 + l16;
      pa[mf] = *(const bf16x8*)((char*)sP + n * 512 + ((ks * 64 + lhi * 16) ^ ((n & 7) << 4)));
    }
#pragma unroll
    for (int nf = 0; nf < 2; ++nf) {
      const int d = wn * 32 + nf * 16 + l16;
      vb[nf] = *(const bf16x8*)(Vp + (size_t)d * 256 + ks * 32 + lhi * 8);
    }
#pragma unroll
    for (int mf = 0; mf < 2; ++mf)
#pragma unroll
      for (int nf = 0; nf < 2; ++nf)
        pacc[mf][nf] = __builtin_amdgcn_mfma_f32_16x16x32_bf16(pa[mf], vb[nf], pacc[mf][nf], 0, 0, 0);
  }
  uint16_t* orow = o + ((size_t)b * 8192 + n0) * 768 + h * 64;
#pragma unroll
  for (int mf = 0; mf < 2; ++mf) {
#pragma unroll
    for (int r = 0; r < 4; ++r) {
      const int n = wm * 32 + mf * 16 + lhi * 4 + r;
      const float inv = recs[n];
#pragma unroll
      for (int nf = 0; nf < 2; ++nf) {
        const int d = wn * 32 + nf * 16 + l16;
        orow[(size_t)n * 768 + d] = f2bf(pacc[mf][nf][r] * inv);
      }
    }
  }
}

// ======== gemm3: NT GEMM, BK=64, 8 waves, 3 LDS buffers, 2-ahead counted-vmcnt
// prefetch, two {stage || ds_read || MFMA} phases per K-tile, XOR swizzle,
// setprio, bijective XCD swizzle. C[M,N] = A[M,K] @ B[N,K]^T.
template <int BM, int BN, bool OUTBF, bool HASBIAS, bool DOGELU, bool HASRES>
__global__ __launch_bounds__(512, 2) void gemm3(
    const uint16_t* __restrict__ A, const uint16_t* __restrict__ B,
    void* __restrict__ Cbase, const float* __restrict__ bias,
    const float* __restrict__ res, int Kd, int lda, int ldb, int ldc) {
  constexpr int WROWS = BM / 4, WCOLS = BN / 2;  // 4x2 waves
  constexpr int FM = WROWS / 16, FN = WCOLS / 16;
  constexpr int IA = BM / 64, IB = BN / 64;
  constexpr int LPT = IA + IB;
  constexpr int ABUF = BM * 64, BBUF = BN * 64;  // u16 elements
  __shared__ __align__(16) uint16_t lds[3 * (ABUF + BBUF)];

  const int nn = gridDim.y;
  const int nwg = gridDim.x * gridDim.y;
  const int bid = blockIdx.y * gridDim.x + blockIdx.x;
  const int q = nwg >> 3, r8 = nwg & 7, xcd = bid & 7, idx = bid >> 3;
  const int wg = (xcd < r8 ? xcd * (q + 1) : r8 * (q + 1) + (xcd - r8) * q) + idx;
  const int bm = wg / nn, bn = wg % nn;
  const int row0 = bm * BM, col0 = bn * BN;

  const int tid = threadIdx.x;
  const int wave = tid >> 6, lane = tid & 63;
  const int wm = wave >> 1, wn = wave & 1;
  const int l16 = lane & 15, lhi = lane >> 4;
  const int srow = tid >> 3, sslot = tid & 7;

  auto stageA = [&](uint16_t* sa, int k0, int j) {
    const int rw = j * 64 + srow;
    const int sp = sslot ^ (rw & 7);
    gload16(A + (size_t)(row0 + rw) * lda + k0 + sp * 8, sa + rw * 64 + sslot * 8);
  };
  auto stageB = [&](uint16_t* sb, int k0, int j) {
    const int rw = j * 64 + srow;
    const int sp = sslot ^ (rw & 7);
    gload16(B + (size_t)(col0 + rw) * ldb + k0 + sp * 8, sb + rw * 64 + sslot * 8);
  };

  f32x4 acc[FM][FN];
#pragma unroll
  for (int m = 0; m < FM; ++m)
#pragma unroll
    for (int n = 0; n < FN; ++n) acc[m][n] = f32x4{0.f, 0.f, 0.f, 0.f};

  const int NT = Kd >> 6;
  // prologue: stage tiles 0 and 1
#pragma unroll
  for (int j = 0; j < IA; ++j) stageA(lds, 0, j);
#pragma unroll
  for (int j = 0; j < IB; ++j) stageB(lds + ABUF, 0, j);
#pragma unroll
  for (int j = 0; j < IA; ++j) stageA(lds + (ABUF + BBUF), 64, j);
#pragma unroll
  for (int j = 0; j < IB; ++j) stageB(lds + (ABUF + BBUF) + ABUF, 64, j);

  for (int t = 0; t < NT; ++t) {
    if (t < NT - 1) waitcnt_vm<LPT>();
    else waitcnt_vm<0>();
    __builtin_amdgcn_s_barrier();
    asm volatile("" ::: "memory");
    const uint16_t* sa = lds + (t % 3) * (ABUF + BBUF);
    const uint16_t* sb = sa + ABUF;
    uint16_t* pa = lds + ((t + 2) % 3) * (ABUF + BBUF);
    uint16_t* pb = pa + ABUF;
    const bool pf = (t + 2) < NT;
    const int k0p = (t + 2) * 64;

    // ---- phase 0 (kstep 0) ----
    if (pf) {
#pragma unroll
      for (int j = 0; j < IA / 2; ++j) stageA(pa, k0p, j);
#pragma unroll
      for (int j = 0; j < IB / 2; ++j) stageB(pb, k0p, j);
    }
    {
      bf16x8 af[FM], bfr[FN];
#pragma unroll
      for (int n = 0; n < FN; ++n) {
        const int rw = wn * WCOLS + n * 16 + l16;
        bfr[n] = *(const bf16x8*)(sb + rw * 64 + ((lhi) ^ (rw & 7)) * 8);
      }
#pragma unroll
      for (int m = 0; m < FM; ++m) {
        const int rw = wm * WROWS + m * 16 + l16;
        af[m] = *(const bf16x8*)(sa + rw * 64 + ((lhi) ^ (rw & 7)) * 8);
      }
      __builtin_amdgcn_s_setprio(1);
#pragma unroll
      for (int m = 0; m < FM; ++m)
#pragma unroll
        for (int n = 0; n < FN; ++n)
          acc[m][n] = __builtin_amdgcn_mfma_f32_16x16x32_bf16(af[m], bfr[n], acc[m][n], 0, 0, 0);
      __builtin_amdgcn_s_setprio(0);
    }
    // ---- phase 1 (kstep 1) ----
    if (pf) {
#pragma unroll
      for (int j = IA / 2; j < IA; ++j) stageA(pa, k0p, j);
#pragma unroll
      for (int j = IB / 2; j < IB; ++j) stageB(pb, k0p, j);
    }
    {
      bf16x8 af[FM], bfr[FN];
#pragma unroll
      for (int n = 0; n < FN; ++n) {
        const int rw = wn * WCOLS + n * 16 + l16;
        bfr[n] = *(const bf16x8*)(sb + rw * 64 + ((4 + lhi) ^ (rw & 7)) * 8);
      }
#pragma unroll
      for (int m = 0; m < FM; ++m) {
        const int rw = wm * WROWS + m * 16 + l16;
        af[m] = *(const bf16x8*)(sa + rw * 64 + ((4 + lhi) ^ (rw & 7)) * 8);
      }
      __builtin_amdgcn_s_setprio(1);
#pragma unroll
      for (int m = 0; m < FM; ++m)
#pragma unroll
        for (int n = 0; n < FN; ++n)
          acc[m][n] = __builtin_amdgcn_mfma_f32_16x16x32_bf16(af[m], bfr[n], acc[m][n], 0, 0, 0);
      __builtin_amdgcn_s_setprio(0);
    }
  }

  float* Cf = (float*)Cbase;
  uint16_t* Cb = (uint16_t*)Cbase;
#pragma unroll
  for (int m = 0; m < FM; ++m) {
#pragma unroll
    for (int n = 0; n < FN; ++n) {
      const int col = col0 + wn * WCOLS + n * 16 + l16;
      float bv = 0.f;
      if (HASBIAS) bv = bias[col];
#pragma unroll
      for (int r = 0; r < 4; ++r) {
        const int row = row0 + wm * WROWS + m * 16 + lhi * 4 + r;
        float v = acc[m][n][r] + bv;
        if (DOGELU) v = gelu_f(v);
        const size_t cidx = (size_t)row * ldc + col;
        if (HASRES) v += res[cidx];
        if (OUTBF) Cb[cidx] = f2bf(v);
        else Cf[cidx] = v;
      }
    }
  }
}

extern "C" void kernel_launch(void* const* d_in, const int* in_sizes, int n_in,
                              void* d_out, int out_size, void* d_ws, size_t ws_size,
                              hipStream_t stream) {
  const float* x      = (const float*)d_in[0];
  const float* ln1_w  = (const float*)d_in[1];
  const float* ln1_b  = (const float*)d_in[2];
  const float* qkv_w  = (const float*)d_in[3];
  const float* qkv_b  = (const float*)d_in[4];
  const float* Ek     = (const float*)d_in[5];
  const float* Ev     = (const float*)d_in[6];
  const float* proj_w = (const float*)d_in[7];
  const float* proj_b = (const float*)d_in[8];
  const float* ln2_w  = (const float*)d_in[9];
  const float* ln2_b  = (const float*)d_in[10];
  const float* fc1_w  = (const float*)d_in[11];
  const float* fc1_b  = (const float*)d_in[12];
  const float* fc2_w  = (const float*)d_in[13];
  const float* fc2_b  = (const float*)d_in[14];
  float* out = (float*)d_out;

  char* w8 = (char*)d_ws;
  size_t off = 0;
  auto take = [&](size_t bytes) { char* p = w8 + off; off += bytes; return p; };
  uint16_t* qkv_wT  = (uint16_t*)take(2304ull * 768 * 2);
  uint16_t* proj_wT = (uint16_t*)take(768ull * 768 * 2);
  uint16_t* fc1_wT  = (uint16_t*)take(3072ull * 768 * 2);
  uint16_t* fc2_wT  = (uint16_t*)take(768ull * 3072 * 2);
  uint16_t* EkT     = (uint16_t*)take(256ull * 8192 * 2);
  uint16_t* EvT     = (uint16_t*)take(256ull * 8192 * 2);
  uint16_t* h_bf    = (uint16_t*)take(16384ull * 768 * 2);
  uint16_t* qkv_bf  = (uint16_t*)take(16384ull * 2304 * 2);
  uint16_t* big     = (uint16_t*)take(100663296ull);             // kv partials -> fc1 out
  uint16_t* kproj   = (uint16_t*)take(2ull * 2 * 256 * 768 * 2); // [kvb][256][768]
  uint16_t* vprojT  = (uint16_t*)take(2ull * 768 * 256 * 2);     // [b][768][256]
  uint16_t* o_bf    = (uint16_t*)take(16384ull * 768 * 2);
  float* part = (float*)big;  // 16 * 196608 * 4B = 12.6 MB, used before fc1
  (void)ws_size; (void)in_sizes; (void)n_in; (void)out_size;

  const dim3 tb(32, 8);
  // 1) weights / projections -> bf16 transposed (all GEMMs NT)
  transpose_f2b<<<dim3(72, 24), tb, 0, stream>>>(qkv_w, qkv_wT, 2304, 768);
  transpose_f2b<<<dim3(24, 24), tb, 0, stream>>>(proj_w, proj_wT, 768, 768);
  transpose_f2b<<<dim3(96, 24), tb, 0, stream>>>(fc1_w, fc1_wT, 3072, 768);
  transpose_f2b<<<dim3(24, 96), tb, 0, stream>>>(fc2_w, fc2_wT, 768, 3072);
  transpose_f2b<<<dim3(8, 256), tb, 0, stream>>>(Ek, EkT, 256, 8192);
  transpose_f2b<<<dim3(8, 256), tb, 0, stream>>>(Ev, EvT, 256, 8192);
  // 2) LN1
  ln768<<<16384, 256, 0, stream>>>(x, ln1_w, ln1_b, h_bf);
  // 3) qkv = h @ qkv_w + b
  gemm3<256, 128, true, true, false, false><<<dim3(64, 18), 512, 0, stream>>>(
      h_bf, qkv_wT, qkv_bf, qkv_b, nullptr, 768, 768, 768, 2304);
  // 4) kv_proj: TN gather GEMM, n-split 4 -> fp32 partials, then reduce
  kv_tn<<<768, 256, 0, stream>>>(EkT, EvT, qkv_bf, part);
  kv_reduce<<<dim3(768, 4), 256, 0, stream>>>(part, kproj);
  // 5) v_projT[b] [768,256]
  for (int b = 0; b < 2; ++b)
    transpose_b2b<<<dim3(24, 8), tb, 0, stream>>>(
        kproj + (size_t)(2 + b) * 196608, vprojT + (size_t)b * 768 * 256, 768, 256);
  // 6) fused attention -> o_bf
  attn_fused<<<dim3(128, 24), 256, 0, stream>>>(qkv_bf, kproj, vprojT, o_bf);
  // 7) x2 = x + o @ proj_w + b -> d_out (fp32)
  gemm3<128, 128, false, true, false, true><<<dim3(128, 6), 512, 0, stream>>>(
      o_bf, proj_wT, out, proj_b, x, 768, 768, 768, 768);
  // 8) LN2
  ln768<<<16384, 256, 0, stream>>>(out, ln2_w, ln2_b, h_bf);
  // 9) a1 = gelu(h2 @ fc1_w + b) -> big
  gemm3<256, 128, true, true, true, false><<<dim3(64, 24), 512, 0, stream>>>(
      h_bf, fc1_wT, big, fc1_b, nullptr, 768, 768, 768, 3072);
  // 10) out = x2 + a1 @ fc2_w + b (in-place residual)
  gemm3<128, 128, false, true, false, true><<<dim3(128, 6), 512, 0, stream>>>(
      big, fc2_wT, out, fc2_b, out, 3072, 3072, 3072, 768);
}